// Round 14
// baseline (250.789 us; speedup 1.0000x reference)
//
#include <hip/hip_runtime.h>
#include <hip/hip_bf16.h>

// (B,T,C,H) = (4,2048,1024,16), D=64
#define Bb 4
#define Tt 2048
#define Cc 1024
#define Hh 16

typedef unsigned short u16;
typedef __attribute__((ext_vector_type(8))) __bf16 bf16x8;
typedef __attribute__((ext_vector_type(4))) float  f32x4;
typedef __attribute__((ext_vector_type(16))) float f32x16;

__device__ __forceinline__ u16 f2bf_hw(float f) {         // native cvt on gfx950
    __bf16 h = (__bf16)f;
    return *(u16*)&h;
}

// v_cvt_pk_bf16_f32: low16 = bf16(a), high16 = bf16(b)
__device__ __forceinline__ unsigned cvt_pk_bf16(float a, float b) {
    unsigned r;
    asm("v_cvt_pk_bf16_f32 %0, %1, %2" : "=v"(r) : "v"(a), "v"(b));
    return r;
}

// v_permlane32_swap_b32: d[32:63] <-> s[0:31]; both registers modified.
__device__ __forceinline__ void plswap(unsigned &d, unsigned &s) {
    asm("v_permlane32_swap_b32 %0, %1" : "+v"(d), "+v"(s));
}

__device__ __forceinline__ float fexp2(float x) {
#if __has_builtin(__builtin_amdgcn_exp2f)
    return __builtin_amdgcn_exp2f(x);
#else
    return __expf(x * 0.6931471805599453f);
#endif
}

__device__ __forceinline__ void gld_lds16(const void* g, void* l) {
    __builtin_amdgcn_global_load_lds(
        (__attribute__((address_space(1))) void*)(g),
        (__attribute__((address_space(3))) void*)(l),
        16, 0, 0);
}

__device__ __forceinline__ f32x4 mfma16(bf16x8 a, bf16x8 b, f32x4 c) {
    return __builtin_amdgcn_mfma_f32_16x16x32_bf16(a, b, c, 0, 0, 0);
}
__device__ __forceinline__ f32x16 mfma32(bf16x8 a, bf16x8 b, f32x16 c) {
    return __builtin_amdgcn_mfma_f32_32x32x16_bf16(a, b, c, 0, 0, 0);
}

// ---------------------------------------------------------------------------
// Fused preprocessing (round-13): one launch for x-cast + 2 weight castT's.
// ---------------------------------------------------------------------------
__device__ void castT_body(const float* __restrict__ in, u16* __restrict__ out,
                           int K, int N, int scaleN, float sv,
                           int bx, int by, float Ls[64][65]) {
    const int n0 = bx * 64, k0 = by * 64;
    const int t = threadIdx.x;
    #pragma unroll
    for (int s = 0; s < 4; ++s) {
        int idx = t + 256 * s;
        int r   = idx >> 4;
        int c4  = (idx & 15) * 4;
        float4 v = *(const float4*)&in[(size_t)(k0 + r) * N + n0 + c4];
        Ls[r][c4 + 0] = v.x; Ls[r][c4 + 1] = v.y;
        Ls[r][c4 + 2] = v.z; Ls[r][c4 + 3] = v.w;
    }
    __syncthreads();
    #pragma unroll
    for (int s = 0; s < 2; ++s) {
        int idx = t + 256 * s;
        int n   = idx >> 3;
        int kc  = (idx & 7) * 8;
        const float sc = (n0 + n < scaleN) ? sv : 1.0f;
        alignas(16) u16 tmp[8];
        #pragma unroll
        for (int i = 0; i < 8; ++i) tmp[i] = f2bf_hw(Ls[kc + i][n] * sc);
        *(uint4*)&out[(size_t)(n0 + n) * K + k0 + kc] = *(const uint4*)tmp;
    }
}

__global__ void prep_cast(const float* __restrict__ x, u16* __restrict__ xb,
                          const float* __restrict__ w_qkv, u16* __restrict__ wqkvT,
                          const float* __restrict__ w_out, u16* __restrict__ woutT,
                          float c2) {
    __shared__ float Ls[64][65];
    const int id = blockIdx.x;
    if (id < 8192) {
        const int i = id * 256 + threadIdx.x;
        float4 v = ((const float4*)x)[i];
        uint2 o;
        o.x = cvt_pk_bf16(v.x, v.y);
        o.y = cvt_pk_bf16(v.z, v.w);
        ((uint2*)xb)[i] = o;
    } else if (id < 8192 + 768) {
        const int r = id - 8192;                 // 48 x 16
        castT_body(w_qkv, wqkvT, Cc, 3 * Cc, Cc, c2, r % 48, r / 48, Ls);
    } else {
        const int r = id - 8960;                 // 16 x 16
        castT_body(w_out, woutT, Cc, Cc, 0, 1.0f, r % 16, r / 16, Ls);
    }
}

// ---------------------------------------------------------------------------
// bf16 GEMM, B^T input — BK=64 m97 structure (round-10 win). gemm2 only.
// ---------------------------------------------------------------------------
__global__ __launch_bounds__(256, 3) void gemm_bt_bf16(
    const u16* __restrict__ A, const u16* __restrict__ Bt,
    const float* __restrict__ bias,
    u16* __restrict__ outB, float* __restrict__ outF,
    int M, int N, int K)
{
    __shared__ u16 As[128 * 64];
    __shared__ u16 Bs[128 * 64];
    const int t = threadIdx.x;
    const int w = t >> 6, lane = t & 63;
    const int quad = lane >> 4, l16 = lane & 15;
    const int wm = w >> 1, wn = w & 1;
    const int m0 = blockIdx.y * 128, n0 = blockIdx.x * 128;

    const int l8r   = lane >> 3;
    const int g_log = (lane & 7) ^ l8r;
    const u16* sAp[4]; const u16* sBp[4];
    #pragma unroll
    for (int u = 0; u < 4; ++u) {
        const int gi = w * 4 + u;
        sAp[u] = A  + (size_t)(m0 + gi * 8 + l8r) * K + g_log * 8;
        sBp[u] = Bt + (size_t)(n0 + gi * 8 + l8r) * K + g_log * 8;
    }
    const int dst0 = w * 2048 + lane * 8;

    int aoff[4][2], boff[4][2];
    #pragma unroll
    for (int i = 0; i < 4; ++i) {
        const int rA = 64 * wm + 16 * i + l16;
        const int rB = 64 * wn + 16 * i + l16;
        #pragma unroll
        for (int kk = 0; kk < 2; ++kk) {
            aoff[i][kk] = rA * 64 + (((4 * kk + quad) ^ (rA & 7)) * 8);
            boff[i][kk] = rB * 64 + (((4 * kk + quad) ^ (rB & 7)) * 8);
        }
    }

    f32x4 acc[4][4] = {};

    for (int k0 = 0; k0 < K; k0 += 64) {
        __syncthreads();
        #pragma unroll
        for (int u = 0; u < 4; ++u) {
            gld_lds16(sAp[u] + k0, (void*)(As + dst0 + u * 512));
            gld_lds16(sBp[u] + k0, (void*)(Bs + dst0 + u * 512));
        }
        asm volatile("s_waitcnt vmcnt(0)" ::: "memory");
        __syncthreads();

        #pragma unroll
        for (int kk = 0; kk < 2; ++kk) {
            bf16x8 af[4], bfr[4];
            #pragma unroll
            for (int i = 0; i < 4; ++i) af[i]  = *(const bf16x8*)&As[aoff[i][kk]];
            #pragma unroll
            for (int j = 0; j < 4; ++j) bfr[j] = *(const bf16x8*)&Bs[boff[j][kk]];
            #pragma unroll
            for (int i = 0; i < 4; ++i)
                #pragma unroll
                for (int j = 0; j < 4; ++j)
                    acc[i][j] = mfma16(af[i], bfr[j], acc[i][j]);
        }
    }

    const int rbase = m0 + 64 * wm + quad * 4;
    const int cbase = n0 + 64 * wn + l16;
    if (outF) {
        float bv[4];
        #pragma unroll
        for (int j = 0; j < 4; ++j) bv[j] = bias[cbase + 16 * j];
        #pragma unroll
        for (int i = 0; i < 4; ++i)
            #pragma unroll
            for (int r = 0; r < 4; ++r) {
                size_t ro = (size_t)(rbase + 16 * i + r) * N;
                #pragma unroll
                for (int j = 0; j < 4; ++j)
                    outF[ro + cbase + 16 * j] = acc[i][j][r] + bv[j];
            }
    } else {
        #pragma unroll
        for (int i = 0; i < 4; ++i)
            #pragma unroll
            for (int r = 0; r < 4; ++r) {
                size_t ro = (size_t)(rbase + 16 * i + r) * N;
                #pragma unroll
                for (int j = 0; j < 4; ++j)
                    outB[ro + cbase + 16 * j] = f2bf_hw(acc[i][j][r]);
            }
    }
}

// ---------------------------------------------------------------------------
// gemm1 with FUSED repack — BK=64 main loop. ROUND-14: epilogue scatters
// into the NEW 32x32-MFMA fragment layouts consumed by attn_mfma32.
// kx32: addr(key,d) = (keyr>>5)*2048 + (d>>4)*512 + ((d>>3)&1)*256
//                     + (keyr&31)*8 + (d&7)            [A-frag, K=16 slabs]
// vx32: addr(key,dv) = (keyr>>5)*2048 + ((keyr>>4)&1)*1024 + (dv>>5)*512
//                     + ((keyr>>3)&1)*256 + (dv&31)*8 + (keyr&7)  [B-frag]
// Both separable row/col; spot-verified vs attn-side addressing for
// (keyr,d) = (37,13), (44,40), (63,63).
// ---------------------------------------------------------------------------
__global__ __launch_bounds__(256, 3) void gemm_qkv_bt(
    const u16* __restrict__ A, const u16* __restrict__ Bt,
    u16* __restrict__ outQ, u16* __restrict__ kx, u16* __restrict__ vx)
{
    const int K = Cc;
    __shared__ u16 As[128 * 64];
    __shared__ u16 Bs[128 * 64];
    const int t = threadIdx.x;
    const int w = t >> 6, lane = t & 63;
    const int quad = lane >> 4, l16 = lane & 15;
    const int wm = w >> 1, wn = w & 1;
    const int m0 = blockIdx.y * 128, n0 = blockIdx.x * 128;

    const int l8r   = lane >> 3;
    const int g_log = (lane & 7) ^ l8r;
    const u16* sAp[4]; const u16* sBp[4];
    #pragma unroll
    for (int u = 0; u < 4; ++u) {
        const int gi = w * 4 + u;
        sAp[u] = A  + (size_t)(m0 + gi * 8 + l8r) * K + g_log * 8;
        sBp[u] = Bt + (size_t)(n0 + gi * 8 + l8r) * K + g_log * 8;
    }
    const int dst0 = w * 2048 + lane * 8;

    int aoff[4][2], boff[4][2];
    #pragma unroll
    for (int i = 0; i < 4; ++i) {
        const int rA = 64 * wm + 16 * i + l16;
        const int rB = 64 * wn + 16 * i + l16;
        #pragma unroll
        for (int kk = 0; kk < 2; ++kk) {
            aoff[i][kk] = rA * 64 + (((4 * kk + quad) ^ (rA & 7)) * 8);
            boff[i][kk] = rB * 64 + (((4 * kk + quad) ^ (rB & 7)) * 8);
        }
    }

    f32x4 acc[4][4] = {};

    for (int k0 = 0; k0 < K; k0 += 64) {
        __syncthreads();
        #pragma unroll
        for (int u = 0; u < 4; ++u) {
            gld_lds16(sAp[u] + k0, (void*)(As + dst0 + u * 512));
            gld_lds16(sBp[u] + k0, (void*)(Bs + dst0 + u * 512));
        }
        asm volatile("s_waitcnt vmcnt(0)" ::: "memory");
        __syncthreads();

        #pragma unroll
        for (int kk = 0; kk < 2; ++kk) {
            bf16x8 af[4], bfr[4];
            #pragma unroll
            for (int i = 0; i < 4; ++i) af[i]  = *(const bf16x8*)&As[aoff[i][kk]];
            #pragma unroll
            for (int j = 0; j < 4; ++j) bfr[j] = *(const bf16x8*)&Bs[boff[j][kk]];
            #pragma unroll
            for (int i = 0; i < 4; ++i)
                #pragma unroll
                for (int j = 0; j < 4; ++j)
                    acc[i][j] = mfma16(af[i], bfr[j], acc[i][j]);
        }
    }

    const int rbase = m0 + 64 * wm + quad * 4;      // + 16*i + r = global row
    const int cbase = n0 + 64 * wn + l16;           // + 16*j    = global col
    const int region = n0 >> 10;                    // 0=Q, 1=K, 2=V (uniform)

    if (region == 0) {
        #pragma unroll
        for (int i = 0; i < 4; ++i)
            #pragma unroll
            for (int r = 0; r < 4; ++r) {
                size_t ro = (size_t)(rbase + 16 * i + r) * Cc;
                #pragma unroll
                for (int j = 0; j < 4; ++j)
                    outQ[ro + cbase + 16 * j] = f2bf_hw(acc[i][j][r]);
            }
    } else if (region == 1) {
        int colK[4];
        #pragma unroll
        for (int j = 0; j < 4; ++j) {
            const int c = (cbase - 1024) + 16 * j;
            const int h = c >> 6, d = c & 63;
            colK[j] = h * 131072 + (d >> 4) * 512 + ((d >> 3) & 1) * 256 + (d & 7);
        }
        #pragma unroll
        for (int i = 0; i < 4; ++i)
            #pragma unroll
            for (int r = 0; r < 4; ++r) {
                const int row = rbase + 16 * i + r;
                const int b = row >> 11, keyb = row & 2047;
                const int ch = keyb >> 6, keyr = keyb & 63;
                const int rowK = b * 2097152 + ch * 4096
                               + (keyr >> 5) * 2048 + (keyr & 31) * 8;
                #pragma unroll
                for (int j = 0; j < 4; ++j)
                    kx[rowK + colK[j]] = f2bf_hw(acc[i][j][r]);
            }
    } else {
        int colV[4];
        #pragma unroll
        for (int j = 0; j < 4; ++j) {
            const int c = (cbase - 2048) + 16 * j;
            const int h = c >> 6, d = c & 63;
            colV[j] = h * 131072 + (d >> 5) * 512 + (d & 31) * 8;
        }
        #pragma unroll
        for (int i = 0; i < 4; ++i)
            #pragma unroll
            for (int r = 0; r < 4; ++r) {
                const int row = rbase + 16 * i + r;
                const int b = row >> 11, keyb = row & 2047;
                const int ch = keyb >> 6, keyr = keyb & 63;
                const int rowV = b * 2097152 + ch * 4096
                               + (keyr >> 5) * 2048 + ((keyr >> 4) & 1) * 1024
                               + ((keyr >> 3) & 1) * 256 + (keyr & 7);
                #pragma unroll
                for (int j = 0; j < 4; ++j)
                    vx[rowV + colV[j]] = f2bf_hw(acc[i][j][r]);
            }
    }
}

// ---------------------------------------------------------------------------
// Flash attention, 32x32 MFMA + fully in-register softmax (T12).
// Round-13 diagnosis: attn is LDS-pipe-bound (~48 LDS ops/chunk/wave ≈ 38us
// of the 72.6). This version eliminates the P LDS roundtrip entirely:
// swapped QK^T (mfma32(K,Q) -> S^T) leaves each lane holding P for q-col
// lane&31; with the 32x32 C layout (row=(reg&3)+8(reg>>2)+4(lane>>5)) the
// PV A-fragment redistribution is a pure lane±32 exchange:
//   pair = v_permlane32_swap_b32(W[2ks][i], W[2ks+1][i])
// fills BOTH output words uniformly across lanes (element-mapping verified
// for all quads/ks). lacc replaced by a 1-reg VALU row-sum + tiny end
// transpose through LDS. 8 waves/block, QBLK=32/wave (256 q/block, grid
// 512 unchanged -> FETCH unchanged), double-buffered KV via global_load_lds.
// No launch-bounds occupancy floor (round-12 lesson): live set ~120 VGPR.
// ---------------------------------------------------------------------------
__global__ __launch_bounds__(512, 1) void attn_mfma32(
    const u16* __restrict__ qb, const u16* __restrict__ kx, const u16* __restrict__ vx,
    const int* __restrict__ mask, u16* __restrict__ outO)
{
    __shared__ u16 KVs[2][8192];      // [buf][ K:0..4095 | V:4096..8191 ] 32KB
    __shared__ float LS[8][64];       // per-wave lsum transpose (2KB)

    const int t = threadIdx.x;
    const int w = t >> 6, lane = t & 63;
    const int c32 = lane & 31, h5 = lane >> 5;
    const int bh = blockIdx.x, qblk = blockIdx.y, b = bh >> 4, hh = bh & 15;

    // ---- valid length L from prefix mask (per-wave) ----
    int sum = 0;
    {
        const int4* mp = (const int4*)(mask + b * Tt) + lane * 8;
        #pragma unroll
        for (int i = 0; i < 8; ++i) { int4 m4 = mp[i]; sum += m4.x + m4.y + m4.z + m4.w; }
        #pragma unroll
        for (int off = 1; off < 64; off <<= 1) sum += __shfl_xor(sum, off);
    }
    const int L = sum;

    // ---- persistent Q fragments (B-operand, pre-scaled at weight cast) ----
    // qf[ds]: Q[q = q0w + c32][d = 16ds + 8*h5 + j]
    const int q0w = qblk * 256 + w * 32;
    bf16x8 qf[4];
    {
        const u16* qp = qb + (size_t)(b * Tt + q0w + c32) * Cc + hh * 64 + h5 * 8;
        #pragma unroll
        for (int ds = 0; ds < 4; ++ds)
            qf[ds] = *(const bf16x8*)(qp + 16 * ds);
    }

    f32x16 oacc[2] = {};
    float ls = 0.f;

    const int nfull = L >> 6;
    const int nch   = (L + 63) >> 6;
    const size_t cb0 = (size_t)bh * 131072;     // 32 chunks * 4096 u16

    // ---- prologue: stage chunk 0 -> buf 0 ----
    gld_lds16(kx + cb0 + t * 8, &KVs[0][t * 8]);
    gld_lds16(vx + cb0 + t * 8, &KVs[0][4096 + t * 8]);
    __syncthreads();

    for (int ch = 0; ch < nch; ++ch) {
        const int p = ch & 1;
        // stage next chunk -> buf p^1 (its readers drained at last barrier)
        const int cc = (ch + 1 < nch) ? ch + 1 : ch;
        const size_t nb = cb0 + (size_t)cc * 4096;
        gld_lds16(kx + nb + t * 8, &KVs[p ^ 1][t * 8]);
        gld_lds16(vx + nb + t * 8, &KVs[p ^ 1][4096 + t * 8]);

        const u16* Kb = KVs[p];
        const u16* Vb = KVs[p] + 4096;

        #pragma unroll
        for (int jt = 0; jt < 2; ++jt) {
            // ---- S^T = K Q^T over 4 d-slabs ----
            f32x16 st = {};
            __builtin_amdgcn_s_setprio(1);
            #pragma unroll
            for (int ds = 0; ds < 4; ++ds) {
                bf16x8 kf = *(const bf16x8*)&Kb[jt * 2048 + ds * 512 + lane * 8];
                st = mfma32(kf, qf[ds], st);
            }
            __builtin_amdgcn_s_setprio(0);

            // ---- exp + mask; row(r) = (r&3)+8*(r>>2)+4*h5 ----
            float e[16];
            if (ch < nfull) {
                #pragma unroll
                for (int r = 0; r < 16; ++r) e[r] = fexp2(st[r]);
            } else {
                const int kcb = ch * 64 + 32 * jt + 4 * h5;
                #pragma unroll
                for (int r = 0; r < 16; ++r) {
                    const int key = kcb + (r & 3) + 8 * (r >> 2);
                    e[r] = (key < L) ? fexp2(st[r]) : 0.f;
                }
            }
            #pragma unroll
            for (int r = 0; r < 16; ++r) ls += e[r];

            // ---- pack to bf16 words; W[s][i] = rows 8s+{2i,2i+1}(+4h5) ----
            unsigned W[4][2];
            #pragma unroll
            for (int s = 0; s < 4; ++s)
                #pragma unroll
                for (int i = 0; i < 2; ++i)
                    W[s][i] = cvt_pk_bf16(e[4 * s + 2 * i], e[4 * s + 2 * i + 1]);

            // ---- PV: per kstep, redistribute via permlane32_swap and mfma ----
            #pragma unroll
            for (int ks = 0; ks < 2; ++ks) {
                unsigned w0 = W[2 * ks][0], w2 = W[2 * ks + 1][0];
                unsigned w1 = W[2 * ks][1], w3 = W[2 * ks + 1][1];
                plswap(w0, w2);     // w0 -> word0 (keys +0,1 / +8,9), w2 -> word2
                plswap(w1, w3);     // w1 -> word1, w3 -> word3
                uint4 pfw = {w0, w1, w2, w3};
                bf16x8 pf = *(const bf16x8*)&pfw;
                __builtin_amdgcn_s_setprio(1);
                #pragma unroll
                for (int dt = 0; dt < 2; ++dt) {
                    bf16x8 vf = *(const bf16x8*)&Vb[jt * 2048 + ks * 1024 + dt * 512 + lane * 8];
                    oacc[dt] = mfma32(pf, vf, oacc[dt]);
                }
                __builtin_amdgcn_s_setprio(0);
            }
        }

        __syncthreads();   // drains staging vmcnt + fences buf reads
    }

    // ---- lsum transpose: lane holds partial for q-col c32 over its rows;
    //      lsum[q] = LS[w][q] + LS[w][q+32] ----
    LS[w][lane] = ls;
    __syncthreads();

    // ---- write O: row = q0w + (r&3)+8*(r>>2)+4*h5, col = hh*64+32dt+c32 ----
    #pragma unroll
    for (int r = 0; r < 16; ++r) {
        const int rowR = (r & 3) + 8 * (r >> 2) + 4 * h5;
        const float inv = 1.f / (LS[w][rowR] + LS[w][rowR + 32]);
        const size_t ro = (size_t)(b * Tt + q0w + rowR) * Cc + hh * 64 + c32;
        outO[ro]      = f2bf_hw(oacc[0][r] * inv);
        outO[ro + 32] = f2bf_hw(oacc[1][r] * inv);
    }
}

// ---------------------------------------------------------------------------
extern "C" void kernel_launch(void* const* d_in, const int* in_sizes, int n_in,
                              void* d_out, int out_size, void* d_ws, size_t ws_size,
                              hipStream_t stream) {
    const float* x     = (const float*)d_in[0];
    const int*   mask  = (const int*)  d_in[1];
    const float* w_qkv = (const float*)d_in[2];
    const float* w_out = (const float*)d_in[3];
    const float* b_out = (const float*)d_in[4];
    float*       outp  = (float*)d_out;

    const int M = Bb * Tt;                        // 8192
    char* ws = (char*)d_ws;
    u16* xb     = (u16*)(ws);                     // 16 MB  [M,C]  (dead after gemm1)
    u16* wqkvT  = (u16*)(ws + (16u << 20));       //  6 MB  [3C,C]
    u16* woutT  = (u16*)(ws + (22u << 20));       //  2 MB  [C,C]
    u16* qbuf   = (u16*)(ws + (24u << 20));       // 16 MB  compact Q [M,C]
    u16* kx     = (u16*)(ws + (40u << 20));       // 16 MB  frag-packed K (32x32)
    u16* vx     = (u16*)(ws + (56u << 20));       // 16 MB  frag-packed V (32x32)
    u16* attnO  = (u16*)(ws);                     // 16 MB  reuses xb region

    const float c2 = 0.18033688011112042f;        // 0.125 * log2(e), folded into Q weights

    // fused preprocessing: 1 launch
    prep_cast<<<9216, 256, 0, stream>>>(x, xb, w_qkv, wqkvT, w_out, woutT, c2);

    // gemm1 with fused repack (BK=64): writes qbuf + kx + vx (32x32 layouts)
    gemm_qkv_bt<<<dim3(3 * Cc / 128, M / 128), 256, 0, stream>>>(
        xb, wqkvT, qbuf, kx, vx);

    // attn: 8-wave blocks, QBLK=32/wave, 32x32 MFMA, in-register softmax
    attn_mfma32<<<dim3(Bb * Hh, Tt / 256), 512, 0, stream>>>(
        qbuf, kx, vx, mask, attnO);

    gemm_bt_bf16<<<dim3(Cc / 128, M / 128), 256, 0, stream>>>(
        attnO, woutT, b_out, nullptr, outp, M, Cc, Cc);
}